// Round 1
// baseline (490.061 us; speedup 1.0000x reference)
//
#include <hip/hip_runtime.h>
#include <math.h>

// LinearAttention (2nd-order derivative-expanded DeltaNet-like), fp32.
// B=2,H=16,S=2048,D=64; n=2; CHUNK=64 real tokens -> 128 virtual rows/chunk.
// Phase 1: per (pair,chunk) forward-substitution (I+A)^{-1}[wc|uc] -> d_ws (64 MiB).
// Phase 2: sequential chunk scan; only s=1 outputs returned; h-update from c=63 only.

namespace {
constexpr int PAIRS = 32;   // B*H
constexpr int SLEN  = 2048;
constexpr int D     = 64;
constexpr int CK    = 64;   // real tokens per chunk
constexpr int CN    = 128;  // virtual rows per chunk
constexpr int NCH   = 32;   // chunks
constexpr int NB    = 8;    // blocks per pair in phase 2

__device__ __forceinline__ float rdlane(float v, int l) {
    return __int_as_float(__builtin_amdgcn_readlane(__float_as_int(v), l));
}

// _stab: nan->0, clip to +-1e4 (also maps +-inf to +-1e4). NaN check must be
// explicit: v_max/v_min drop NaN to a bound instead of propagating.
__device__ __forceinline__ float stab1(float x) {
    float y = fminf(fmaxf(x, -10000.f), 10000.f);
    return (x != x) ? 0.f : y;
}
} // namespace

// ---------------- Phase 1: per-chunk WY solve ----------------
// grid = PAIRS*NCH, block = 256. LDS: Y[128][132] + strip[128][8] = 70KB -> 2 blk/CU.
__global__ __launch_bounds__(256, 2)
void la_phase1(const float* __restrict__ kg, const float* __restrict__ vg,
               const float* __restrict__ bg, float* __restrict__ ws)
{
    __shared__ float Ysh[CN][132];   // rows = virtual tokens, cols 0-63 = wci, 64-127 = uci
    __shared__ float scm[CN][8];     // A-strip, col-major: scm[j][r] = A[8g+r][j]

    const int blk = blockIdx.x;
    const int p  = blk / NCH, nc = blk % NCH;
    const int tid = threadIdx.x;
    const int baseT = nc * CK;
    const float* kp = kg + (size_t)p * SLEN * D;
    const float* vp = vg + (size_t)p * SLEN * D;
    const float* bp = bg + (size_t)p * SLEN;

    // ---- Y init: row i = 2c+s: [coef_s * beta[t] * k[t-s] | coef_s * beta[t] * v[t-s]]
    {
        int i = tid >> 1, half = tid & 1;     // half 0 = w cols, 1 = u cols
        int c = i >> 1, s = i & 1;
        int t = baseT + c;
        int srcT = t - s;
        float coef = s ? 0.5f : -0.5f;
        float scale = coef * bp[t];
        const float* src = (half == 0) ? kp : vp;
        if (srcT >= 0) {
            const float4* row4 = (const float4*)(src + (size_t)srcT * D);
            #pragma unroll
            for (int d4 = 0; d4 < 16; ++d4) {
                float4 val = row4[d4];
                val.x *= scale; val.y *= scale; val.z *= scale; val.w *= scale;
                *(float4*)&Ysh[i][half * 64 + d4 * 4] = val;
            }
        } else {
            #pragma unroll
            for (int d4 = 0; d4 < 16; ++d4)
                *(float4*)&Ysh[i][half * 64 + d4 * 4] = float4{0.f, 0.f, 0.f, 0.f};
        }
    }

    const int col = tid;  // substitution column for tid < 128

    for (int g = 0; g < 16; ++g) {
        __syncthreads();   // protects scm from previous group's readers
        // ---- strip: A[8g+r][j] for j in [0, 8g+8), all 256 threads.
        // A[i][j] = sgn*0.25*beta[t_i]*dot(k[t_i - s_i], k[t_j - s_j]); zero-padded rows -> 0.
        const int jmax = 8 * g + 8;
        for (int e = tid; e < 8 * jmax; e += 256) {
            int j = e >> 3, r = e & 7;
            int i = 8 * g + r;
            int ci = i >> 1, si = i & 1;
            int ti = baseT + ci;
            int ga = ti - si;
            int cj = j >> 1, sj = j & 1;
            int gb = baseT + cj - sj;
            float aval = 0.f;
            if (ga >= 0 && gb >= 0) {
                const float4* ka = (const float4*)(kp + (size_t)ga * D);
                const float4* kb = (const float4*)(kp + (size_t)gb * D);
                float dot = 0.f;
                #pragma unroll
                for (int d4 = 0; d4 < 16; ++d4) {
                    float4 a = ka[d4], b = kb[d4];
                    dot += a.x * b.x + a.y * b.y + a.z * b.z + a.w * b.w;
                }
                float sgn = (si == sj) ? 0.25f : -0.25f;
                aval = sgn * bp[ti] * dot;
            }
            scm[j][r] = aval;
        }
        __syncthreads();
        // ---- substitution for rows 8g..8g+7; each lane owns one column (no cross-lane deps)
        if (col < CN) {
            float acc[8] = {0.f, 0.f, 0.f, 0.f, 0.f, 0.f, 0.f, 0.f};
            for (int j = 0; j < 8 * g; ++j) {
                float yv = Ysh[j][col];
                float4 a03 = *(const float4*)&scm[j][0];
                float4 a47 = *(const float4*)&scm[j][4];
                acc[0] += a03.x * yv; acc[1] += a03.y * yv;
                acc[2] += a03.z * yv; acc[3] += a03.w * yv;
                acc[4] += a47.x * yv; acc[5] += a47.y * yv;
                acc[6] += a47.z * yv; acc[7] += a47.w * yv;
            }
            float yn[8];
            #pragma unroll
            for (int r = 0; r < 8; ++r) {
                float val = Ysh[8 * g + r][col] - acc[r];
                #pragma unroll
                for (int rp = 0; rp < 8; ++rp) {
                    if (rp < r) val -= scm[8 * g + rp][r] * yn[rp];
                }
                yn[r] = val;
                Ysh[8 * g + r][col] = val;
            }
        }
    }
    __syncthreads();
    // ---- write [wci|uci] to workspace, unpadded [128][128]
    float* gY = ws + (size_t)blk * (CN * CN);
    for (int idx = tid; idx < CN * 32; idx += 256) {
        int r = idx >> 5, c4 = idx & 31;
        float4 val = *(const float4*)&Ysh[r][c4 * 4];
        *(float4*)&gY[r * CN + c4 * 4] = val;
    }
}

// ---------------- Phase 2: sequential chunk scan ----------------
namespace {
template <bool WRITE_OUT>
__device__ __forceinline__ void process_pos(
    const float* __restrict__ gY, const float* __restrict__ qp,
    float (&hreg)[64], int nc, int c, int lane,
    float& uv0_out, float& uv1_out, float& w0_out, float& w1_out,
    float* __restrict__ op)
{
    const int t = nc * CK + c;
    float w0l = gY[(2 * c) * CN + lane];
    float u0l = gY[(2 * c) * CN + 64 + lane];
    float w1l = gY[(2 * c + 1) * CN + lane];
    float u1l = gY[(2 * c + 1) * CN + 64 + lane];
    float q1l = (t > 0) ? 0.5f * qp[(size_t)(t - 1) * D + lane] : 0.f;

    // uval0[e] = u0[e] - sum_d w0[d] * h[d][e]
    float kh0a = 0.f, kh0b = 0.f;
    #pragma unroll
    for (int d = 0; d < 64; d += 2) {
        kh0a += rdlane(w0l, d)     * hreg[d];
        kh0b += rdlane(w0l, d + 1) * hreg[d + 1];
    }
    float uv0 = u0l - (kh0a + kh0b);

    // st1[d][e] = stab(h[d][e] + w0[d]*uv0[e]); kh1 = w1.st1, o_inter = q1.st1
    float kh = 0.f, oac = 0.f;
    #pragma unroll
    for (int d = 0; d < 64; ++d) {
        float st = stab1(hreg[d] + rdlane(w0l, d) * uv0);
        kh += rdlane(w1l, d) * st;
        if (WRITE_OUT) oac += rdlane(q1l, d) * st;
    }
    float uv1 = u1l - kh;
    if (WRITE_OUT) op[(size_t)t * D + lane] = q1l * uv1 + oac;
    uv0_out = uv0; uv1_out = uv1; w0_out = w0l; w1_out = w1l;
}
} // namespace

// grid = PAIRS*NB (256 blocks, 1/CU), block = 512 (8 waves; wave w owns position 8*nb+w).
__global__ __launch_bounds__(512, 2)
void la_phase2(const float* __restrict__ qg, const float* __restrict__ ws,
               float* __restrict__ outg)
{
    __shared__ float hsh[D][66];   // h[d][e], pad 66 -> conflict-free column reads
    __shared__ float uv0s[D], uv1s[D], w0s[D], w1s[D];

    const int blk = blockIdx.x;
    const int p = blk / NB, nb = blk % NB;
    const int tid = threadIdx.x;
    const int wave = tid >> 6, lane = tid & 63;
    const int cOut = nb * 8 + wave;

    for (int idx = tid; idx < D * 66; idx += 512) (&hsh[0][0])[idx] = 0.f;
    __syncthreads();

    const float* qp = qg + (size_t)p * SLEN * D;
    float* op = outg + (size_t)p * SLEN * D;

    for (int nc = 0; nc < NCH; ++nc) {
        const float* gY = ws + ((size_t)p * NCH + nc) * (CN * CN);

        // private copy of h column e=lane
        float hreg[64];
        #pragma unroll
        for (int d = 0; d < 64; ++d) hreg[d] = hsh[d][lane];

        float uv0, uv1, w0l, w1l;
        process_pos<true>(gY, qp, hreg, nc, cOut, lane, uv0, uv1, w0l, w1l, op);
        if (cOut == 63) { uv0s[lane] = uv0; uv1s[lane] = uv1; w0s[lane] = w0l; w1s[lane] = w1l; }
        // every block needs the c=63 chain for the h update; wave 7 replicates it
        if (wave == 7 && nb != 7) {
            process_pos<false>(gY, qp, hreg, nc, 63, lane, uv0, uv1, w0l, w1l, op);
            uv0s[lane] = uv0; uv1s[lane] = uv1; w0s[lane] = w0l; w1s[lane] = w1l;
        }
        __syncthreads();

        // h update: state2 = stab(stab(h + w0_63 x uv0_63) + w1_63 x uv1_63) at c=63,
        // then h' = (state2/2) * gelu_tanh(2*state2 / (rownorm + 1e-6)).
        {
            const int d = tid >> 3;
            const int e0 = (tid & 7) * 8;
            float w0d = w0s[d], w1d = w1s[d];
            float st2v[8];
            float ssum = 0.f;
            #pragma unroll
            for (int j = 0; j < 8; ++j) {
                float st1 = stab1(hsh[d][e0 + j] + w0d * uv0s[e0 + j]);
                float st2 = stab1(st1 + w1d * uv1s[e0 + j]);
                st2v[j] = st2;
                ssum += st2 * st2;
            }
            ssum += __shfl_xor(ssum, 1);
            ssum += __shfl_xor(ssum, 2);
            ssum += __shfl_xor(ssum, 4);
            float xn = sqrtf(ssum) + 1e-6f;
            #pragma unroll
            for (int j = 0; j < 8; ++j) {
                float x = st2v[j];
                float y = (2.f * x) / xn;
                float gl = 0.5f * y * (1.f + tanhf(0.7978845608028654f * (y + 0.044715f * y * y * y)));
                hsh[d][e0 + j] = x * 0.5f * gl;
            }
        }
        __syncthreads();
    }
}

extern "C" void kernel_launch(void* const* d_in, const int* in_sizes, int n_in,
                              void* d_out, int out_size, void* d_ws, size_t ws_size,
                              hipStream_t stream)
{
    (void)in_sizes; (void)n_in; (void)out_size; (void)ws_size;
    const float* q    = (const float*)d_in[0];
    const float* k    = (const float*)d_in[1];
    const float* v    = (const float*)d_in[2];
    const float* beta = (const float*)d_in[3];
    float* ws  = (float*)d_ws;    // needs 32*32*128*128*4 = 64 MiB
    float* out = (float*)d_out;

    la_phase1<<<PAIRS * NCH, 256, 0, stream>>>(k, v, beta, ws);
    la_phase2<<<PAIRS * NB, 512, 0, stream>>>(q, ws, out);
}

// Round 2
// 378.944 us; speedup vs baseline: 1.2932x; 1.2932x over previous
//
#include <hip/hip_runtime.h>
#include <math.h>

// LinearAttention (2nd-order derivative-expanded DeltaNet-like), fp32.
// B=2,H=16,S=2048,D=64; n=2; CHUNK=64 real tokens -> 128 virtual rows/chunk.
// Phase 1: Gram-matrix + per-(chunk,col-half) forward substitution -> d_ws (64 MiB).
// Phase 2: sequential chunk scan; only s=1 outputs returned; h-update from c=63 only.

namespace {
constexpr int PAIRS = 32;   // B*H
constexpr int SLEN  = 2048;
constexpr int D     = 64;
constexpr int CK    = 64;   // real tokens per chunk
constexpr int CN    = 128;  // virtual rows per chunk
constexpr int NCH   = 32;   // chunks
constexpr int NB2   = 16;   // blocks per pair in phase 2

// _stab: nan->0, clip to +-1e4 (also maps +-inf to +-1e4). NaN check must be
// explicit: min/max drop NaN to a bound instead of propagating.
__device__ __forceinline__ float stab1(float x) {
    float y = fminf(fmaxf(x, -10000.f), 10000.f);
    return (x != x) ? 0.f : y;
}

// swizzled float-index into kst: row a, float4 index f4 (0..15), stride 68 floats.
__device__ __forceinline__ int kidx(int a, int f4) {
    return a * 68 + 4 * (f4 ^ ((a >> 2) & 3));
}
} // namespace

// ---------------- Phase 1: Gram matrix + per-chunk WY solve ----------------
// grid = PAIRS*NCH*2 (2048): block owns 64 of the 128 Y columns. 256 threads.
// LDS: Ysh 32KB + G 17.2KB + union(kst | scm+redsh) 17.3KB + beta 0.5KB = 67.6KB -> 2 blk/CU.
__global__ __launch_bounds__(256, 2)
void la_phase1(const float* __restrict__ kg, const float* __restrict__ vg,
               const float* __restrict__ bg, float* __restrict__ ws)
{
    __shared__ float Ysh[CN][64];          // this block's 64-column half
    __shared__ float Gm[65][66];           // Gram matrix of k rows [baseT-1 .. baseT+63]
    __shared__ char  ureg[17680];          // kst[65][68] then reused as scm+redsh
    __shared__ float bq4[CK], bh[CK];

    float* kstf = (float*)ureg;                         // kst flat (swizzled via kidx)
    float* scm  = (float*)ureg;                         // [2][128][8] = 8192 B
    float (*redsh)[66] = (float(*)[66])(ureg + 8192);   // [24][66]   = 6336 B

    const int blk  = blockIdx.x;
    const int p    = blk >> 6;
    const int nc   = (blk >> 1) & 31;
    const int half = blk & 1;
    const int tid  = threadIdx.x;
    const int lane = tid & 63;
    const int m    = tid >> 6;
    const int baseT = nc * CK;
    const float* kp = kg + (size_t)p * SLEN * D;
    const float* vp = vg + (size_t)p * SLEN * D;
    const float* bp = bg + (size_t)p * SLEN;

    // ---- stage k rows a=0..64  <- k[baseT-1+a] (row 0 zero when baseT==0)
    for (int u = tid; u < 65 * 16; u += 256) {
        int a = u >> 4, f4 = u & 15;
        int src = baseT - 1 + a;
        float4 val = float4{0.f, 0.f, 0.f, 0.f};
        if (src >= 0) val = ((const float4*)(kp + (size_t)src * D))[f4];
        *(float4*)&kstf[kidx(a, f4)] = val;
    }
    if (tid < CK) {
        float bv = bp[baseT + tid];
        bq4[tid] = 0.25f * bv;
        bh[tid]  = 0.5f  * bv;
    }
    __syncthreads();

    // ---- Y init for this half (rows i=2c+s). half0: coef*beta*k (from LDS),
    //      half1: coef*beta*v (global). coef: s=1 -> +0.5, s=0 -> -0.5.
    for (int u = tid; u < CN * 16; u += 256) {
        int i = u >> 4, f4 = u & 15;
        int ci = i >> 1, si = i & 1;
        float sc = si ? bh[ci] : -bh[ci];
        float4 val = float4{0.f, 0.f, 0.f, 0.f};
        if (half == 0) {
            int ai = ci - si + 1;
            val = *(const float4*)&kstf[kidx(ai, f4)];
        } else {
            int srcT = baseT + ci - si;
            if (srcT >= 0) val = ((const float4*)(vp + (size_t)srcT * D))[f4];
        }
        val.x *= sc; val.y *= sc; val.z *= sc; val.w *= sc;
        *(float4*)&Ysh[i][f4 * 4] = val;
    }

    // ---- Gram matrix, 4x4 register tiles, lower-triangular tile set + mirror
    for (int tt = tid; tt < 17 * 17; tt += 256) {
        int ta = tt / 17, tb = tt % 17;
        if (tb > ta) continue;
        int a0 = ta * 4, b0 = tb * 4;
        float acc[4][4] = {};
        for (int d4 = 0; d4 < 16; ++d4) {
            float4 av[4], bv[4];
            #pragma unroll
            for (int r = 0; r < 4; ++r) {
                av[r] = *(const float4*)&kstf[kidx(min(a0 + r, 64), d4)];
                bv[r] = *(const float4*)&kstf[kidx(min(b0 + r, 64), d4)];
            }
            #pragma unroll
            for (int r = 0; r < 4; ++r)
                #pragma unroll
                for (int c = 0; c < 4; ++c)
                    acc[r][c] += av[r].x * bv[c].x + av[r].y * bv[c].y
                               + av[r].z * bv[c].z + av[r].w * bv[c].w;
        }
        #pragma unroll
        for (int r = 0; r < 4; ++r)
            #pragma unroll
            for (int c = 0; c < 4; ++c)
                if (a0 + r <= 64 && b0 + c <= 64) {
                    Gm[a0 + r][b0 + c] = acc[r][c];
                    Gm[b0 + c][a0 + r] = acc[r][c];
                }
    }
    __syncthreads();

    // strip(g): scm[g&1][j][r] = A[8g+r][j] for j < 8g+8.
    // A[i][j] = sgn*0.25*beta[t_i]*G[a_i][a_j], sgn=+1 iff s_i==s_j; a = (i>>1)-(i&1)+1.
    auto stripf = [&](int g, int t0, int tstride) {
        int buf = g & 1;
        int jmax = 8 * g + 8;
        for (int e = t0; e < 8 * jmax; e += tstride) {
            int j = e >> 3, r = e & 7;
            int i = 8 * g + r;
            int ai = (i >> 1) - (i & 1) + 1;
            int aj = (j >> 1) - (j & 1) + 1;
            float sgn = ((i ^ j) & 1) ? -1.f : 1.f;
            scm[(buf * CN + j) * 8 + r] = sgn * bq4[i >> 1] * Gm[ai][aj];
        }
    };

    stripf(0, tid, 256);
    __syncthreads();

    const int col = lane;
    for (int g = 0; g < 16; ++g) {
        const int buf = g & 1;
        // Phase A: partial acc over previous rows, wave m handles j === m (mod 4)
        float acc[8] = {};
        for (int j = m; j < 8 * g; j += 4) {
            float yv = Ysh[j][col];
            const float4 a03 = *(const float4*)&scm[(buf * CN + j) * 8];
            const float4 a47 = *(const float4*)&scm[(buf * CN + j) * 8 + 4];
            acc[0] += a03.x * yv; acc[1] += a03.y * yv;
            acc[2] += a03.z * yv; acc[3] += a03.w * yv;
            acc[4] += a47.x * yv; acc[5] += a47.y * yv;
            acc[6] += a47.z * yv; acc[7] += a47.w * yv;
        }
        if (m > 0) {
            #pragma unroll
            for (int r = 0; r < 8; ++r) redsh[(m - 1) * 8 + r][col] = acc[r];
        }
        __syncthreads();
        // Phase B: wave 0 reduces + solves rows 8g..8g+7; waves 1-3 build strip(g+1)
        if (m == 0) {
            float yn[8];
            #pragma unroll
            for (int r = 0; r < 8; ++r) {
                float val = Ysh[8 * g + r][col] - acc[r]
                          - redsh[r][col] - redsh[8 + r][col] - redsh[16 + r][col];
                #pragma unroll
                for (int rp = 0; rp < 8; ++rp)
                    if (rp < r) val -= scm[(buf * CN + 8 * g + rp) * 8 + r] * yn[rp];
                yn[r] = val;
                Ysh[8 * g + r][col] = val;
            }
        } else if (g < 15) {
            stripf(g + 1, tid - 64, 192);
        }
        __syncthreads();
    }

    // ---- writeback this half's columns
    float* gY = ws + (size_t)(p * NCH + nc) * (CN * CN) + half * 64;
    for (int u = tid; u < CN * 16; u += 256) {
        int r = u >> 4, f4 = u & 15;
        *(float4*)&gY[r * CN + f4 * 4] = *(const float4*)&Ysh[r][f4 * 4];
    }
}

// ---------------- Phase 2: sequential chunk scan ----------------
// grid = PAIRS*NB2 (512, 2 blocks/CU), block = 256 (4 waves; wave owns position nb*4+wave).
__global__ __launch_bounds__(256, 2)
void la_phase2(const float* __restrict__ qg, const float* __restrict__ ws,
               float* __restrict__ outg)
{
    __shared__ float hsh[D][66];      // h[d][e]
    __shared__ float wbr[4][3][64];   // per-wave broadcast rows {w0,w1,q1}
    __shared__ float uv0s[D], uv1s[D], w0s[D], w1s[D];

    const int blk  = blockIdx.x;
    const int p    = blk >> 4, nb = blk & 15;
    const int tid  = threadIdx.x;
    const int wave = tid >> 6, lane = tid & 63;
    const int cOut = nb * 4 + wave;
    const bool own63 = (cOut == 63);

    for (int idx = tid; idx < D * 66; idx += 256) (&hsh[0][0])[idx] = 0.f;
    __syncthreads();

    const float* qp = qg + (size_t)p * SLEN * D;
    float* op = outg + (size_t)p * SLEN * D;
    const float* wsbase = ws + (size_t)p * NCH * (CN * CN);

    // per-position pipeline registers (own position + optional c=63 replica)
    float w0n = 0.f, u0n = 0.f, w1n = 0.f, u1n = 0.f, q1n = 0.f;
    float w0n2 = 0.f, u0n2 = 0.f, w1n2 = 0.f, u1n2 = 0.f, q1n2 = 0.f;
    {
        const float* gY = wsbase;
        w0n = gY[(2 * cOut) * CN + lane];
        u0n = gY[(2 * cOut) * CN + 64 + lane];
        w1n = gY[(2 * cOut + 1) * CN + lane];
        u1n = gY[(2 * cOut + 1) * CN + 64 + lane];
        q1n = (cOut > 0) ? 0.5f * qp[(size_t)(cOut - 1) * D + lane] : 0.f;
        if (nb != 15 && wave == 0) {   // replica holder for nc=0 is wave (0&3)=0
            w0n2 = gY[126 * CN + lane];
            u0n2 = gY[126 * CN + 64 + lane];
            w1n2 = gY[127 * CN + lane];
            u1n2 = gY[127 * CN + 64 + lane];
            q1n2 = 0.5f * qp[(size_t)62 * D + lane];
        }
    }

    // one position's work: broadcast via wave-private LDS slot, two d-passes
    auto process = [&](float w0c, float u0c, float w1c, float u1c, float q1c,
                       const float (&hreg)[64], bool wr, int t,
                       float& uv0o, float& uv1o) {
        wbr[wave][0][lane] = w0c;
        wbr[wave][1][lane] = w1c;
        wbr[wave][2][lane] = q1c;
        float kh0 = 0.f;
        #pragma unroll
        for (int d4 = 0; d4 < 16; ++d4) {
            float4 w4 = *(const float4*)&wbr[wave][0][d4 * 4];
            kh0 += w4.x * hreg[4 * d4]     + w4.y * hreg[4 * d4 + 1]
                 + w4.z * hreg[4 * d4 + 2] + w4.w * hreg[4 * d4 + 3];
        }
        float uv0 = u0c - kh0;
        float kh = 0.f, oac = 0.f;
        #pragma unroll
        for (int d4 = 0; d4 < 16; ++d4) {
            float4 w04 = *(const float4*)&wbr[wave][0][d4 * 4];
            float4 w14 = *(const float4*)&wbr[wave][1][d4 * 4];
            float4 q14 = *(const float4*)&wbr[wave][2][d4 * 4];
            float st0 = stab1(hreg[4 * d4]     + w04.x * uv0);
            float st1 = stab1(hreg[4 * d4 + 1] + w04.y * uv0);
            float st2 = stab1(hreg[4 * d4 + 2] + w04.z * uv0);
            float st3 = stab1(hreg[4 * d4 + 3] + w04.w * uv0);
            kh  += w14.x * st0 + w14.y * st1 + w14.z * st2 + w14.w * st3;
            oac += q14.x * st0 + q14.y * st1 + q14.z * st2 + q14.w * st3;
        }
        float uv1 = u1c - kh;
        if (wr) op[(size_t)t * D + lane] = q1c * uv1 + oac;
        uv0o = uv0; uv1o = uv1;
    };

    for (int nc = 0; nc < NCH; ++nc) {
        const float w0c = w0n, u0c = u0n, w1c = w1n, u1c = u1n, q1c = q1n;
        const float w0c2 = w0n2, u0c2 = u0n2, w1c2 = w1n2, u1c2 = u1n2, q1c2 = q1n2;
        const bool rep63 = (nb != 15) && (wave == (nc & 3));

        // prefetch next chunk's rows (hidden under this chunk's compute)
        if (nc + 1 < NCH) {
            const float* gY = wsbase + (size_t)(nc + 1) * (CN * CN);
            const int t = (nc + 1) * CK + cOut;
            w0n = gY[(2 * cOut) * CN + lane];
            u0n = gY[(2 * cOut) * CN + 64 + lane];
            w1n = gY[(2 * cOut + 1) * CN + lane];
            u1n = gY[(2 * cOut + 1) * CN + 64 + lane];
            q1n = 0.5f * qp[(size_t)(t - 1) * D + lane];
            if (nb != 15 && wave == ((nc + 1) & 3)) {
                w0n2 = gY[126 * CN + lane];
                u0n2 = gY[126 * CN + 64 + lane];
                w1n2 = gY[127 * CN + lane];
                u1n2 = gY[127 * CN + 64 + lane];
                q1n2 = 0.5f * qp[(size_t)((nc + 1) * CK + 62) * D + lane];
            }
        }

        float hreg[64];
        #pragma unroll
        for (int d = 0; d < 64; ++d) hreg[d] = hsh[d][lane];

        float uv0, uv1;
        process(w0c, u0c, w1c, u1c, q1c, hreg, true, nc * CK + cOut, uv0, uv1);
        if (own63) {
            uv0s[lane] = uv0; uv1s[lane] = uv1; w0s[lane] = w0c; w1s[lane] = w1c;
        }
        if (rep63) {
            float uv0b, uv1b;
            process(w0c2, u0c2, w1c2, u1c2, q1c2, hreg, false, 0, uv0b, uv1b);
            uv0s[lane] = uv0b; uv1s[lane] = uv1b; w0s[lane] = w0c2; w1s[lane] = w1c2;
        }
        __syncthreads();

        // h update at c=63: state2 = stab(stab(h + w0 x uv0) + w1 x uv1), then
        // h' = (state2/2) * gelu_tanh(2*state2 / (rownorm + 1e-6)).
        {
            const int d  = tid >> 2;
            const int e0 = (tid & 3) * 16;
            float w0d = w0s[d], w1d = w1s[d];
            float st2v[16];
            float ssum = 0.f;
            #pragma unroll
            for (int j = 0; j < 16; ++j) {
                float st1 = stab1(hsh[d][e0 + j] + w0d * uv0s[e0 + j]);
                float st2 = stab1(st1 + w1d * uv1s[e0 + j]);
                st2v[j] = st2;
                ssum += st2 * st2;
            }
            ssum += __shfl_xor(ssum, 1);
            ssum += __shfl_xor(ssum, 2);
            float xn = sqrtf(ssum) + 1e-6f;
            #pragma unroll
            for (int j = 0; j < 16; ++j) {
                float x = st2v[j];
                float y = (2.f * x) / xn;
                float gl = 0.5f * y * (1.f + tanhf(0.7978845608028654f * (y + 0.044715f * y * y * y)));
                hsh[d][e0 + j] = x * 0.5f * gl;
            }
        }
        __syncthreads();
    }
}

extern "C" void kernel_launch(void* const* d_in, const int* in_sizes, int n_in,
                              void* d_out, int out_size, void* d_ws, size_t ws_size,
                              hipStream_t stream)
{
    (void)in_sizes; (void)n_in; (void)out_size; (void)ws_size;
    const float* q    = (const float*)d_in[0];
    const float* k    = (const float*)d_in[1];
    const float* v    = (const float*)d_in[2];
    const float* beta = (const float*)d_in[3];
    float* ws  = (float*)d_ws;    // 32*32*128*128*4 = 64 MiB
    float* out = (float*)d_out;

    la_phase1<<<PAIRS * NCH * 2, 256, 0, stream>>>(k, v, beta, ws);
    la_phase2<<<PAIRS * NB2, 256, 0, stream>>>(q, ws, out);
}

// Round 3
// 335.960 us; speedup vs baseline: 1.4587x; 1.1279x over previous
//
#include <hip/hip_runtime.h>
#include <math.h>

// LinearAttention (2nd-order derivative-expanded DeltaNet-like), fp32.
// B=2,H=16,S=2048,D=64; n=2; CHUNK=64 real tokens -> 128 virtual rows/chunk.
// Phase 1: Gram-matrix + per-(chunk,col-half) forward substitution -> d_ws (64 MiB).
// Phase 2: sequential chunk scan; only s=1 outputs returned; h-update from c=63 only.

namespace {
constexpr int PAIRS = 32;   // B*H
constexpr int SLEN  = 2048;
constexpr int D     = 64;
constexpr int CK    = 64;   // real tokens per chunk
constexpr int CN    = 128;  // virtual rows per chunk
constexpr int NCH   = 32;   // chunks
constexpr int NB2   = 8;    // blocks per pair in phase 2 (8 waves/block, 1 position/wave)

// _stab: nan->0, clip to +-1e4 (also maps +-inf to +-1e4). Clip is load-bearing:
// w*uv products genuinely overflow (1e27*1e33). NaN check must be explicit.
__device__ __forceinline__ float stab1(float x) {
    float y = __builtin_amdgcn_fmed3f(x, -10000.f, 10000.f);  // clamp, 1 inst
    return (x != x) ? 0.f : y;
}

// swizzled float-index into kst: row a, float4 index f4 (0..15), stride 68 floats.
__device__ __forceinline__ int kidx(int a, int f4) {
    return a * 68 + 4 * (f4 ^ ((a >> 2) & 3));
}
} // namespace

// ---------------- Phase 1: Gram matrix + per-chunk WY solve ----------------
// grid = PAIRS*NCH*2 (2048): block owns 64 of the 128 Y columns. 256 threads.
__global__ __launch_bounds__(256, 2)
void la_phase1(const float* __restrict__ kg, const float* __restrict__ vg,
               const float* __restrict__ bg, float* __restrict__ ws)
{
    __shared__ float Ysh[CN][64];          // this block's 64-column half
    __shared__ float Gm[65][66];           // Gram matrix of k rows [baseT-1 .. baseT+63]
    __shared__ char  ureg[17680];          // kst[65][68] then reused as scm+redsh
    __shared__ float bq4[CK], bh[CK];

    float* kstf = (float*)ureg;                         // kst flat (swizzled via kidx)
    float* scm  = (float*)ureg;                         // [2][128][8] = 8192 B
    float (*redsh)[66] = (float(*)[66])(ureg + 8192);   // [24][66]   = 6336 B

    const int blk  = blockIdx.x;
    const int p    = blk >> 6;
    const int nc   = (blk >> 1) & 31;
    const int half = blk & 1;
    const int tid  = threadIdx.x;
    const int lane = tid & 63;
    const int m    = tid >> 6;
    const int baseT = nc * CK;
    const float* kp = kg + (size_t)p * SLEN * D;
    const float* vp = vg + (size_t)p * SLEN * D;
    const float* bp = bg + (size_t)p * SLEN;

    // ---- stage k rows a=0..64  <- k[baseT-1+a] (row 0 zero when baseT==0)
    for (int u = tid; u < 65 * 16; u += 256) {
        int a = u >> 4, f4 = u & 15;
        int src = baseT - 1 + a;
        float4 val = float4{0.f, 0.f, 0.f, 0.f};
        if (src >= 0) val = ((const float4*)(kp + (size_t)src * D))[f4];
        *(float4*)&kstf[kidx(a, f4)] = val;
    }
    if (tid < CK) {
        float bv = bp[baseT + tid];
        bq4[tid] = 0.25f * bv;
        bh[tid]  = 0.5f  * bv;
    }
    __syncthreads();

    // ---- Y init for this half (rows i=2c+s). half0: coef*beta*k (from LDS),
    //      half1: coef*beta*v (global). coef: s=1 -> +0.5, s=0 -> -0.5.
    for (int u = tid; u < CN * 16; u += 256) {
        int i = u >> 4, f4 = u & 15;
        int ci = i >> 1, si = i & 1;
        float sc = si ? bh[ci] : -bh[ci];
        float4 val = float4{0.f, 0.f, 0.f, 0.f};
        if (half == 0) {
            int ai = ci - si + 1;
            val = *(const float4*)&kstf[kidx(ai, f4)];
        } else {
            int srcT = baseT + ci - si;
            if (srcT >= 0) val = ((const float4*)(vp + (size_t)srcT * D))[f4];
        }
        val.x *= sc; val.y *= sc; val.z *= sc; val.w *= sc;
        *(float4*)&Ysh[i][f4 * 4] = val;
    }

    // ---- Gram matrix, 4x4 register tiles, lower-triangular tile set + mirror
    for (int tt = tid; tt < 17 * 17; tt += 256) {
        int ta = tt / 17, tb = tt % 17;
        if (tb > ta) continue;
        int a0 = ta * 4, b0 = tb * 4;
        float acc[4][4] = {};
        for (int d4 = 0; d4 < 16; ++d4) {
            float4 av[4], bv[4];
            #pragma unroll
            for (int r = 0; r < 4; ++r) {
                av[r] = *(const float4*)&kstf[kidx(min(a0 + r, 64), d4)];
                bv[r] = *(const float4*)&kstf[kidx(min(b0 + r, 64), d4)];
            }
            #pragma unroll
            for (int r = 0; r < 4; ++r)
                #pragma unroll
                for (int c = 0; c < 4; ++c)
                    acc[r][c] += av[r].x * bv[c].x + av[r].y * bv[c].y
                               + av[r].z * bv[c].z + av[r].w * bv[c].w;
        }
        #pragma unroll
        for (int r = 0; r < 4; ++r)
            #pragma unroll
            for (int c = 0; c < 4; ++c)
                if (a0 + r <= 64 && b0 + c <= 64) {
                    Gm[a0 + r][b0 + c] = acc[r][c];
                    Gm[b0 + c][a0 + r] = acc[r][c];
                }
    }
    __syncthreads();

    // strip(g): scm[g&1][j][r] = A[8g+r][j] for j < 8g+8.
    // A[i][j] = sgn*0.25*beta[t_i]*G[a_i][a_j], sgn=+1 iff s_i==s_j; a = (i>>1)-(i&1)+1.
    auto stripf = [&](int g, int t0, int tstride) {
        int buf = g & 1;
        int jmax = 8 * g + 8;
        for (int e = t0; e < 8 * jmax; e += tstride) {
            int j = e >> 3, r = e & 7;
            int i = 8 * g + r;
            int ai = (i >> 1) - (i & 1) + 1;
            int aj = (j >> 1) - (j & 1) + 1;
            float sgn = ((i ^ j) & 1) ? -1.f : 1.f;
            scm[(buf * CN + j) * 8 + r] = sgn * bq4[i >> 1] * Gm[ai][aj];
        }
    };

    stripf(0, tid, 256);
    __syncthreads();

    const int col = lane;
    for (int g = 0; g < 16; ++g) {
        const int buf = g & 1;
        // Phase A: partial acc over previous rows, wave m handles j === m (mod 4)
        float acc[8] = {};
        for (int j = m; j < 8 * g; j += 4) {
            float yv = Ysh[j][col];
            const float4 a03 = *(const float4*)&scm[(buf * CN + j) * 8];
            const float4 a47 = *(const float4*)&scm[(buf * CN + j) * 8 + 4];
            acc[0] += a03.x * yv; acc[1] += a03.y * yv;
            acc[2] += a03.z * yv; acc[3] += a03.w * yv;
            acc[4] += a47.x * yv; acc[5] += a47.y * yv;
            acc[6] += a47.z * yv; acc[7] += a47.w * yv;
        }
        if (m > 0) {
            #pragma unroll
            for (int r = 0; r < 8; ++r) redsh[(m - 1) * 8 + r][col] = acc[r];
        }
        __syncthreads();
        // Phase B: wave 0 reduces + solves rows 8g..8g+7; waves 1-3 build strip(g+1)
        if (m == 0) {
            float yn[8];
            #pragma unroll
            for (int r = 0; r < 8; ++r) {
                float val = Ysh[8 * g + r][col] - acc[r]
                          - redsh[r][col] - redsh[8 + r][col] - redsh[16 + r][col];
                #pragma unroll
                for (int rp = 0; rp < 8; ++rp)
                    if (rp < r) val -= scm[(buf * CN + 8 * g + rp) * 8 + r] * yn[rp];
                yn[r] = val;
                Ysh[8 * g + r][col] = val;
            }
        } else if (g < 15) {
            stripf(g + 1, tid - 64, 192);
        }
        __syncthreads();
    }

    // ---- writeback this half's columns
    float* gY = ws + (size_t)(p * NCH + nc) * (CN * CN) + half * 64;
    for (int u = tid; u < CN * 16; u += 256) {
        int r = u >> 4, f4 = u & 15;
        *(float4*)&gY[r * CN + f4 * 4] = *(const float4*)&Ysh[r][f4 * 4];
    }
}

// ---------------- Phase 2: sequential chunk scan ----------------
// grid = PAIRS*NB2 (256 blocks, 1/CU), block = 512 (8 waves; wave owns position nb*8+wave).
__global__ __launch_bounds__(512, 2)
void la_phase2(const float* __restrict__ qg, const float* __restrict__ ws,
               float* __restrict__ outg)
{
    __shared__ float hsh[D][65];      // h[d][e]; 65 === 1 (mod 32) -> both access modes 2-way free
    __shared__ float wbr[8][3][64];   // per-wave broadcast rows {w0,w1,q1}
    __shared__ float uv0s[D], uv1s[D], w0s[D], w1s[D];

    const int blk  = blockIdx.x;
    const int p    = blk >> 3, nb = blk & 7;
    const int tid  = threadIdx.x;
    const int wave = tid >> 6, lane = tid & 63;
    const int cOut = nb * 8 + wave;
    const bool own63 = (cOut == 63);

    for (int idx = tid; idx < D * 65; idx += 512) (&hsh[0][0])[idx] = 0.f;
    __syncthreads();

    const float* qp = qg + (size_t)p * SLEN * D;
    float* op = outg + (size_t)p * SLEN * D;
    const float* wsbase = ws + (size_t)p * NCH * (CN * CN);

    // per-position pipeline registers (own position + optional c=63 replica)
    float w0n = 0.f, u0n = 0.f, w1n = 0.f, u1n = 0.f, q1n = 0.f;
    float w0n2 = 0.f, u0n2 = 0.f, w1n2 = 0.f, u1n2 = 0.f, q1n2 = 0.f;
    {
        const float* gY = wsbase;
        w0n = gY[(2 * cOut) * CN + lane];
        u0n = gY[(2 * cOut) * CN + 64 + lane];
        w1n = gY[(2 * cOut + 1) * CN + lane];
        u1n = gY[(2 * cOut + 1) * CN + 64 + lane];
        q1n = (cOut > 0) ? 0.5f * qp[(size_t)(cOut - 1) * D + lane] : 0.f;
        if (nb != 7 && wave == 0) {   // replica holder for nc=0 is wave (0&7)=0
            w0n2 = gY[126 * CN + lane];
            u0n2 = gY[126 * CN + 64 + lane];
            w1n2 = gY[127 * CN + lane];
            u1n2 = gY[127 * CN + 64 + lane];
            q1n2 = 0.5f * qp[(size_t)62 * D + lane];
        }
    }

    // one position's work: broadcast via wave-private LDS slot, two d-passes
    auto process = [&](float w0c, float u0c, float w1c, float u1c, float q1c,
                       const float (&hreg)[64], bool wr, int t,
                       float& uv0o, float& uv1o) {
        wbr[wave][0][lane] = w0c;
        wbr[wave][1][lane] = w1c;
        wbr[wave][2][lane] = q1c;
        float kh0 = 0.f;
        #pragma unroll
        for (int d4 = 0; d4 < 16; ++d4) {
            float4 w4 = *(const float4*)&wbr[wave][0][d4 * 4];
            kh0 += w4.x * hreg[4 * d4]     + w4.y * hreg[4 * d4 + 1]
                 + w4.z * hreg[4 * d4 + 2] + w4.w * hreg[4 * d4 + 3];
        }
        float uv0 = u0c - kh0;
        float kh = 0.f, oac = 0.f;
        #pragma unroll
        for (int d4 = 0; d4 < 16; ++d4) {
            float4 w04 = *(const float4*)&wbr[wave][0][d4 * 4];
            float4 w14 = *(const float4*)&wbr[wave][1][d4 * 4];
            float4 q14 = *(const float4*)&wbr[wave][2][d4 * 4];
            float st0 = stab1(hreg[4 * d4]     + w04.x * uv0);
            float st1 = stab1(hreg[4 * d4 + 1] + w04.y * uv0);
            float st2 = stab1(hreg[4 * d4 + 2] + w04.z * uv0);
            float st3 = stab1(hreg[4 * d4 + 3] + w04.w * uv0);
            kh  += w14.x * st0 + w14.y * st1 + w14.z * st2 + w14.w * st3;
            oac += q14.x * st0 + q14.y * st1 + q14.z * st2 + q14.w * st3;
        }
        float uv1 = u1c - kh;
        if (wr) op[(size_t)t * D + lane] = q1c * uv1 + oac;
        uv0o = uv0; uv1o = uv1;
    };

    for (int nc = 0; nc < NCH; ++nc) {
        const float w0c = w0n, u0c = u0n, w1c = w1n, u1c = u1n, q1c = q1n;
        const float w0c2 = w0n2, u0c2 = u0n2, w1c2 = w1n2, u1c2 = u1n2, q1c2 = q1n2;
        const bool rep63 = (nb != 7) && (wave == (nc & 7));

        // prefetch next chunk's rows (hidden under this chunk's compute)
        if (nc + 1 < NCH) {
            const float* gY = wsbase + (size_t)(nc + 1) * (CN * CN);
            const int t = (nc + 1) * CK + cOut;
            w0n = gY[(2 * cOut) * CN + lane];
            u0n = gY[(2 * cOut) * CN + 64 + lane];
            w1n = gY[(2 * cOut + 1) * CN + lane];
            u1n = gY[(2 * cOut + 1) * CN + 64 + lane];
            q1n = 0.5f * qp[(size_t)(t - 1) * D + lane];
            if (nb != 7 && wave == ((nc + 1) & 7)) {
                w0n2 = gY[126 * CN + lane];
                u0n2 = gY[126 * CN + 64 + lane];
                w1n2 = gY[127 * CN + lane];
                u1n2 = gY[127 * CN + 64 + lane];
                q1n2 = 0.5f * qp[(size_t)((nc + 1) * CK + 62) * D + lane];
            }
        }

        float hreg[64];
        #pragma unroll
        for (int d = 0; d < 64; ++d) hreg[d] = hsh[d][lane];

        float uv0, uv1;
        process(w0c, u0c, w1c, u1c, q1c, hreg, true, nc * CK + cOut, uv0, uv1);
        if (own63) {
            uv0s[lane] = uv0; uv1s[lane] = uv1; w0s[lane] = w0c; w1s[lane] = w1c;
        }
        if (rep63) {
            float uv0b, uv1b;
            process(w0c2, u0c2, w1c2, u1c2, q1c2, hreg, false, 0, uv0b, uv1b);
            uv0s[lane] = uv0b; uv1s[lane] = uv1b; w0s[lane] = w0c2; w1s[lane] = w1c2;
        }
        __syncthreads();

        // h update at c=63: state2 = stab(stab(h + w0 x uv0) + w1 x uv1), then
        // h' = x/2 * gelu_tanh(2x/xn) = 0.25*x*y*(1+tanh(z)), y=2x/xn, xn = rownorm+1e-6.
        // tanh via hardware exp2: tanh(z) = (e-1)/(e+1), e = 2^(y*(c1+c3*y^2)); y in [-2,2].
        {
            const int d  = tid >> 3;          // row (norm axis is e)
            const int e0 = (tid & 7) * 8;     // 8 elements per thread
            float w0d = w0s[d], w1d = w1s[d];
            float st2v[8];
            float ssum = 0.f;
            #pragma unroll
            for (int j = 0; j < 8; ++j) {
                float st1 = stab1(hsh[d][e0 + j] + w0d * uv0s[e0 + j]);
                float st2 = stab1(st1 + w1d * uv1s[e0 + j]);
                st2v[j] = st2;
                ssum += st2 * st2;
            }
            ssum += __shfl_xor(ssum, 1);
            ssum += __shfl_xor(ssum, 2);
            ssum += __shfl_xor(ssum, 4);
            float xn = __builtin_amdgcn_sqrtf(ssum) + 1e-6f;
            float s2 = 2.f * __builtin_amdgcn_rcpf(xn);
            #pragma unroll
            for (int j = 0; j < 8; ++j) {
                float x  = st2v[j];
                float y  = x * s2;                       // in [-2, 2]
                float y2 = y * y;
                float arg = y * (2.3022078f + 0.1029432f * y2);  // 2*log2e*z
                float e  = __builtin_amdgcn_exp2f(arg);
                float t  = (e - 1.f) * __builtin_amdgcn_rcpf(e + 1.f);
                hsh[d][e0 + j] = 0.25f * x * y * (1.f + t);
            }
        }
        __syncthreads();
    }
}

extern "C" void kernel_launch(void* const* d_in, const int* in_sizes, int n_in,
                              void* d_out, int out_size, void* d_ws, size_t ws_size,
                              hipStream_t stream)
{
    (void)in_sizes; (void)n_in; (void)out_size; (void)ws_size;
    const float* q    = (const float*)d_in[0];
    const float* k    = (const float*)d_in[1];
    const float* v    = (const float*)d_in[2];
    const float* beta = (const float*)d_in[3];
    float* ws  = (float*)d_ws;    // 32*32*128*128*4 = 64 MiB
    float* out = (float*)d_out;

    la_phase1<<<PAIRS * NCH * 2, 256, 0, stream>>>(k, v, beta, ws);
    la_phase2<<<PAIRS * NB2, 512, 0, stream>>>(q, ws, out);
}

// Round 4
// 300.110 us; speedup vs baseline: 1.6329x; 1.1195x over previous
//
#include <hip/hip_runtime.h>
#include <math.h>

// LinearAttention (2nd-order derivative-expanded DeltaNet-like), fp32.
// B=2,H=16,S=2048,D=64; n=2; CHUNK=64 real tokens -> 128 virtual rows/chunk.
// Phase 1: Gram-matrix + per-(chunk,col-half) forward substitution -> d_ws (64 MiB).
// Phase 2: cooperative d-sliced chunk scan; h lives in registers (wave w owns rows
//          [8w,8w+8), column e=lane); all dot products split 8-ways across waves.

namespace {
constexpr int PAIRS = 32;   // B*H
constexpr int SLEN  = 2048;
constexpr int D     = 64;
constexpr int CK    = 64;   // real tokens per chunk
constexpr int CN    = 128;  // virtual rows per chunk
constexpr int NCH   = 32;   // chunks
constexpr int NB2   = 8;    // blocks per pair in phase 2

// _stab: nan->0, clip to +-1e4 (also maps +-inf to +-1e4). Clip is load-bearing:
// w*uv products genuinely overflow (1e27*1e33). NaN check must be explicit.
__device__ __forceinline__ float stab1(float x) {
    float y = __builtin_amdgcn_fmed3f(x, -10000.f, 10000.f);  // clamp, 1 inst
    return (x != x) ? 0.f : y;
}

// swizzled float-index into kst: row a, float4 index f4 (0..15), stride 68 floats.
__device__ __forceinline__ int kidx(int a, int f4) {
    return a * 68 + 4 * (f4 ^ ((a >> 2) & 3));
}
} // namespace

// ---------------- Phase 1: Gram matrix + per-chunk WY solve ----------------
// grid = PAIRS*NCH*2 (2048): block owns 64 of the 128 Y columns. 256 threads.
__global__ __launch_bounds__(256, 2)
void la_phase1(const float* __restrict__ kg, const float* __restrict__ vg,
               const float* __restrict__ bg, float* __restrict__ ws)
{
    __shared__ float Ysh[CN][64];          // this block's 64-column half
    __shared__ float Gm[65][66];           // Gram matrix of k rows [baseT-1 .. baseT+63]
    __shared__ char  ureg[17680];          // kst[65][68] then reused as scm+redsh
    __shared__ float bq4[CK], bh[CK];

    float* kstf = (float*)ureg;                         // kst flat (swizzled via kidx)
    float* scm  = (float*)ureg;                         // [2][128][8] = 8192 B
    float (*redsh)[66] = (float(*)[66])(ureg + 8192);   // [24][66]   = 6336 B

    const int blk  = blockIdx.x;
    const int p    = blk >> 6;
    const int nc   = (blk >> 1) & 31;
    const int half = blk & 1;
    const int tid  = threadIdx.x;
    const int lane = tid & 63;
    const int m    = tid >> 6;
    const int baseT = nc * CK;
    const float* kp = kg + (size_t)p * SLEN * D;
    const float* vp = vg + (size_t)p * SLEN * D;
    const float* bp = bg + (size_t)p * SLEN;

    // ---- stage k rows a=0..64  <- k[baseT-1+a] (row 0 zero when baseT==0)
    for (int u = tid; u < 65 * 16; u += 256) {
        int a = u >> 4, f4 = u & 15;
        int src = baseT - 1 + a;
        float4 val = float4{0.f, 0.f, 0.f, 0.f};
        if (src >= 0) val = ((const float4*)(kp + (size_t)src * D))[f4];
        *(float4*)&kstf[kidx(a, f4)] = val;
    }
    if (tid < CK) {
        float bv = bp[baseT + tid];
        bq4[tid] = 0.25f * bv;
        bh[tid]  = 0.5f  * bv;
    }
    __syncthreads();

    // ---- Y init for this half (rows i=2c+s). half0: coef*beta*k (from LDS),
    //      half1: coef*beta*v (global). coef: s=1 -> +0.5, s=0 -> -0.5.
    for (int u = tid; u < CN * 16; u += 256) {
        int i = u >> 4, f4 = u & 15;
        int ci = i >> 1, si = i & 1;
        float sc = si ? bh[ci] : -bh[ci];
        float4 val = float4{0.f, 0.f, 0.f, 0.f};
        if (half == 0) {
            int ai = ci - si + 1;
            val = *(const float4*)&kstf[kidx(ai, f4)];
        } else {
            int srcT = baseT + ci - si;
            if (srcT >= 0) val = ((const float4*)(vp + (size_t)srcT * D))[f4];
        }
        val.x *= sc; val.y *= sc; val.z *= sc; val.w *= sc;
        *(float4*)&Ysh[i][f4 * 4] = val;
    }

    // ---- Gram matrix, 4x4 register tiles, lower-triangular tile set + mirror
    for (int tt = tid; tt < 17 * 17; tt += 256) {
        int ta = tt / 17, tb = tt % 17;
        if (tb > ta) continue;
        int a0 = ta * 4, b0 = tb * 4;
        float acc[4][4] = {};
        for (int d4 = 0; d4 < 16; ++d4) {
            float4 av[4], bv[4];
            #pragma unroll
            for (int r = 0; r < 4; ++r) {
                av[r] = *(const float4*)&kstf[kidx(min(a0 + r, 64), d4)];
                bv[r] = *(const float4*)&kstf[kidx(min(b0 + r, 64), d4)];
            }
            #pragma unroll
            for (int r = 0; r < 4; ++r)
                #pragma unroll
                for (int c = 0; c < 4; ++c)
                    acc[r][c] += av[r].x * bv[c].x + av[r].y * bv[c].y
                               + av[r].z * bv[c].z + av[r].w * bv[c].w;
        }
        #pragma unroll
        for (int r = 0; r < 4; ++r)
            #pragma unroll
            for (int c = 0; c < 4; ++c)
                if (a0 + r <= 64 && b0 + c <= 64) {
                    Gm[a0 + r][b0 + c] = acc[r][c];
                    Gm[b0 + c][a0 + r] = acc[r][c];
                }
    }
    __syncthreads();

    // strip(g): scm[g&1][j][r] = A[8g+r][j] for j < 8g+8.
    // A[i][j] = sgn*0.25*beta[t_i]*G[a_i][a_j], sgn=+1 iff s_i==s_j; a = (i>>1)-(i&1)+1.
    auto stripf = [&](int g, int t0, int tstride) {
        int buf = g & 1;
        int jmax = 8 * g + 8;
        for (int e = t0; e < 8 * jmax; e += tstride) {
            int j = e >> 3, r = e & 7;
            int i = 8 * g + r;
            int ai = (i >> 1) - (i & 1) + 1;
            int aj = (j >> 1) - (j & 1) + 1;
            float sgn = ((i ^ j) & 1) ? -1.f : 1.f;
            scm[(buf * CN + j) * 8 + r] = sgn * bq4[i >> 1] * Gm[ai][aj];
        }
    };

    stripf(0, tid, 256);
    __syncthreads();

    const int col = lane;
    for (int g = 0; g < 16; ++g) {
        const int buf = g & 1;
        // Phase A: partial acc over previous rows, wave m handles j === m (mod 4)
        float acc[8] = {};
        for (int j = m; j < 8 * g; j += 4) {
            float yv = Ysh[j][col];
            const float4 a03 = *(const float4*)&scm[(buf * CN + j) * 8];
            const float4 a47 = *(const float4*)&scm[(buf * CN + j) * 8 + 4];
            acc[0] += a03.x * yv; acc[1] += a03.y * yv;
            acc[2] += a03.z * yv; acc[3] += a03.w * yv;
            acc[4] += a47.x * yv; acc[5] += a47.y * yv;
            acc[6] += a47.z * yv; acc[7] += a47.w * yv;
        }
        if (m > 0) {
            #pragma unroll
            for (int r = 0; r < 8; ++r) redsh[(m - 1) * 8 + r][col] = acc[r];
        }
        __syncthreads();
        // Phase B: wave 0 reduces + solves rows 8g..8g+7; waves 1-3 build strip(g+1)
        if (m == 0) {
            float yn[8];
            #pragma unroll
            for (int r = 0; r < 8; ++r) {
                float val = Ysh[8 * g + r][col] - acc[r]
                          - redsh[r][col] - redsh[8 + r][col] - redsh[16 + r][col];
                #pragma unroll
                for (int rp = 0; rp < 8; ++rp)
                    if (rp < r) val -= scm[(buf * CN + 8 * g + rp) * 8 + r] * yn[rp];
                yn[r] = val;
                Ysh[8 * g + r][col] = val;
            }
        } else if (g < 15) {
            stripf(g + 1, tid - 64, 192);
        }
        __syncthreads();
    }

    // ---- writeback this half's columns
    float* gY = ws + (size_t)(p * NCH + nc) * (CN * CN) + half * 64;
    for (int u = tid; u < CN * 16; u += 256) {
        int r = u >> 4, f4 = u & 15;
        *(float4*)&gY[r * CN + f4 * 4] = *(const float4*)&Ysh[r][f4 * 4];
    }
}

// ---------------- Phase 2: cooperative d-sliced chunk scan ----------------
// grid = PAIRS*NB2 (256 blocks), block = 512 (8 waves).
// Wave w holds h rows [8w,8w+8) (column e=lane) in registers. 9 positions per
// block per chunk: P=0..7 -> c = nb*8+P (outputs), P=8 -> c=63 (h-update chain).
__global__ __launch_bounds__(512)
void la_phase2(const float* __restrict__ qg, const float* __restrict__ ws,
               float* __restrict__ outg)
{
    __shared__ float WU[2][9][256];    // staged [w0|u0|w1|u1] per position, dbuf
    __shared__ float Qs[2][9][64];     // staged raw q rows (scale 0.5 applied at end)
    __shared__ float partA[8][9][64];  // d-slice partials (kh0, then kh1)
    __shared__ float partB[8][9][64];  // d-slice partials (oac)
    __shared__ float UV0[9][64];       // uv0 per position
    __shared__ float UV1r[64];         // uv1 at c=63

    const int blk  = blockIdx.x;
    const int p    = blk >> 3, nb = blk & 7;
    const int tid  = threadIdx.x;
    const int w    = tid >> 6, lane = tid & 63;

    const float* qp = qg + (size_t)p * SLEN * D;
    float* op = outg + (size_t)p * SLEN * D;
    const float* wsbase = ws + (size_t)p * NCH * (CN * CN);

    const int cMain = nb * 8 + w;      // this wave's staging/reduction position (P=w)

    // staging registers (loaded at chunk top, written to LDS at chunk bottom)
    float4 wuR = float4{0.f, 0.f, 0.f, 0.f};
    float  qR  = 0.f;
    float4 wuR2 = float4{0.f, 0.f, 0.f, 0.f};
    float  qR2  = 0.f;

    auto stage_load = [&](int nc) {
        const float* gY = wsbase + (size_t)nc * (CN * CN);
        wuR = *(const float4*)(gY + (size_t)(2 * cMain) * CN + lane * 4);
        int t = nc * CK + cMain;
        int srcT = (t > 0) ? t - 1 : 0;
        qR = qp[(size_t)srcT * D + lane];
        if (w == 0) {
            wuR2 = *(const float4*)(gY + (size_t)(2 * 63) * CN + lane * 4);
            qR2 = qp[(size_t)(nc * CK + 62) * D + lane];
        }
    };
    auto stage_write = [&](int buf) {
        *(float4*)&WU[buf][w][lane * 4] = wuR;
        Qs[buf][w][lane] = qR;
        if (w == 0) {
            *(float4*)&WU[buf][8][lane * 4] = wuR2;
            Qs[buf][8][lane] = qR2;
        }
    };

    float hs[8];
    #pragma unroll
    for (int j = 0; j < 8; ++j) hs[j] = 0.f;

    stage_load(0);
    stage_write(0);
    __syncthreads();

    for (int nc = 0; nc < NCH; ++nc) {
        const int buf = nc & 1;
        if (nc + 1 < NCH) stage_load(nc + 1);   // issue early; write at chunk bottom

        // ---- ROUND 1: kh0 partials over d-slice [8w,8w+8)
        #pragma unroll
        for (int P = 0; P < 9; ++P) {
            float4 a = *(const float4*)&WU[buf][P][8 * w];
            float4 b = *(const float4*)&WU[buf][P][8 * w + 4];
            float s = ((a.x * hs[0] + a.y * hs[1]) + (a.z * hs[2] + a.w * hs[3]))
                    + ((b.x * hs[4] + b.y * hs[5]) + (b.z * hs[6] + b.w * hs[7]));
            partA[w][P][lane] = s;
        }
        __syncthreads();

        // ---- REDUCE 1: uv0[P][e] = u0[P][e] - sum_w partials
        {
            float s = 0.f;
            #pragma unroll
            for (int wv = 0; wv < 8; ++wv) s += partA[wv][w][lane];
            UV0[w][lane] = WU[buf][w][64 + lane] - s;
        }
        if (w == 0) {
            float s = 0.f;
            #pragma unroll
            for (int wv = 0; wv < 8; ++wv) s += partA[wv][8][lane];
            UV0[8][lane] = WU[buf][8][64 + lane] - s;
        }
        __syncthreads();

        // ---- ROUND 2: st1 = stab(h + w0*uv0); kh1/oac partials over d-slice
        #pragma unroll
        for (int P = 0; P < 9; ++P) {
            float uv0 = UV0[P][lane];
            float4 w0a = *(const float4*)&WU[buf][P][8 * w];
            float4 w0b = *(const float4*)&WU[buf][P][8 * w + 4];
            float4 w1a = *(const float4*)&WU[buf][P][128 + 8 * w];
            float4 w1b = *(const float4*)&WU[buf][P][128 + 8 * w + 4];
            float4 qa  = *(const float4*)&Qs[buf][P][8 * w];
            float4 qb  = *(const float4*)&Qs[buf][P][8 * w + 4];
            float st0 = stab1(hs[0] + w0a.x * uv0);
            float st1 = stab1(hs[1] + w0a.y * uv0);
            float st2 = stab1(hs[2] + w0a.z * uv0);
            float st3 = stab1(hs[3] + w0a.w * uv0);
            float st4 = stab1(hs[4] + w0b.x * uv0);
            float st5 = stab1(hs[5] + w0b.y * uv0);
            float st6 = stab1(hs[6] + w0b.z * uv0);
            float st7 = stab1(hs[7] + w0b.w * uv0);
            float kh = ((w1a.x * st0 + w1a.y * st1) + (w1a.z * st2 + w1a.w * st3))
                     + ((w1b.x * st4 + w1b.y * st5) + (w1b.z * st6 + w1b.w * st7));
            float oa = ((qa.x * st0 + qa.y * st1) + (qa.z * st2 + qa.w * st3))
                     + ((qb.x * st4 + qb.y * st5) + (qb.z * st6 + qb.w * st7));
            partA[w][P][lane] = kh;
            partB[w][P][lane] = oa;
        }
        __syncthreads();

        // ---- REDUCE 2: outputs for P=0..7; uv1_63 from P=8
        {
            float skh = 0.f, soa = 0.f;
            #pragma unroll
            for (int wv = 0; wv < 8; ++wv) {
                skh += partA[wv][w][lane];
                soa += partB[wv][w][lane];
            }
            float uv1 = WU[buf][w][192 + lane] - skh;
            int t = nc * CK + cMain;
            float qlane = Qs[buf][w][lane];
            float outv = 0.5f * (qlane * uv1 + soa);
            op[(size_t)t * D + lane] = (t > 0) ? outv : 0.f;
        }
        if (w == 0) {
            float skh = 0.f;
            #pragma unroll
            for (int wv = 0; wv < 8; ++wv) skh += partA[wv][8][lane];
            UV1r[lane] = WU[buf][8][192 + lane] - skh;
        }
        __syncthreads();

        // ---- H-UPDATE (fully in registers): rows [8w,8w+8), column e=lane.
        // state2 = stab(stab(h + w0_63 x uv0_63) + w1_63 x uv1_63);
        // h' = 0.25*x*y*(1+tanh(z)), y = 2x/(rownorm+1e-6). Norm over e -> butterfly.
        {
            float uv0l = UV0[8][lane];
            float uv1l = UV1r[lane];
            float4 w0a = *(const float4*)&WU[buf][8][8 * w];
            float4 w0b = *(const float4*)&WU[buf][8][8 * w + 4];
            float4 w1a = *(const float4*)&WU[buf][8][128 + 8 * w];
            float4 w1b = *(const float4*)&WU[buf][8][128 + 8 * w + 4];
            float st2v[8], ss[8];
            st2v[0] = stab1(stab1(hs[0] + w0a.x * uv0l) + w1a.x * uv1l);
            st2v[1] = stab1(stab1(hs[1] + w0a.y * uv0l) + w1a.y * uv1l);
            st2v[2] = stab1(stab1(hs[2] + w0a.z * uv0l) + w1a.z * uv1l);
            st2v[3] = stab1(stab1(hs[3] + w0a.w * uv0l) + w1a.w * uv1l);
            st2v[4] = stab1(stab1(hs[4] + w0b.x * uv0l) + w1b.x * uv1l);
            st2v[5] = stab1(stab1(hs[5] + w0b.y * uv0l) + w1b.y * uv1l);
            st2v[6] = stab1(stab1(hs[6] + w0b.z * uv0l) + w1b.z * uv1l);
            st2v[7] = stab1(stab1(hs[7] + w0b.w * uv0l) + w1b.w * uv1l);
            #pragma unroll
            for (int j = 0; j < 8; ++j) ss[j] = st2v[j] * st2v[j];
            #pragma unroll
            for (int msk = 1; msk < 64; msk <<= 1) {
                #pragma unroll
                for (int j = 0; j < 8; ++j) ss[j] += __shfl_xor(ss[j], msk);
            }
            #pragma unroll
            for (int j = 0; j < 8; ++j) {
                float xn = __builtin_amdgcn_sqrtf(ss[j]) + 1e-6f;
                float y  = 2.f * st2v[j] * __builtin_amdgcn_rcpf(xn);  // in [-2,2]
                float y2 = y * y;
                float e  = __builtin_amdgcn_exp2f(y * (2.3022078f + 0.1029432f * y2));
                float th = (e - 1.f) * __builtin_amdgcn_rcpf(e + 1.f);
                hs[j] = 0.25f * st2v[j] * y * (1.f + th);
            }
        }

        if (nc + 1 < NCH) stage_write(buf ^ 1);
        __syncthreads();
    }
}

extern "C" void kernel_launch(void* const* d_in, const int* in_sizes, int n_in,
                              void* d_out, int out_size, void* d_ws, size_t ws_size,
                              hipStream_t stream)
{
    (void)in_sizes; (void)n_in; (void)out_size; (void)ws_size;
    const float* q    = (const float*)d_in[0];
    const float* k    = (const float*)d_in[1];
    const float* v    = (const float*)d_in[2];
    const float* beta = (const float*)d_in[3];
    float* ws  = (float*)d_ws;    // 32*32*128*128*4 = 64 MiB
    float* out = (float*)d_out;

    la_phase1<<<PAIRS * NCH * 2, 256, 0, stream>>>(k, v, beta, ws);
    la_phase2<<<PAIRS * NB2, 512, 0, stream>>>(q, ws, out);
}